// Round 3
// baseline (1333.834 us; speedup 1.0000x reference)
//
#include <hip/hip_runtime.h>

#define NN 4096
#define BB 8
#define BN 32768
#define HID 64

__device__ __forceinline__ float sigmoidf_(float x){ return 1.f / (1.f + __expf(-x)); }

// ---- tiny precompute: As[j*4+h], Ad[j*4+h], cE[h*3+e] ----
__global__ void prep_kernel(const float* __restrict__ W_gat,
                            const float* __restrict__ att_src,
                            const float* __restrict__ att_dst,
                            const float* __restrict__ W_edge,
                            const float* __restrict__ att_edge,
                            float* __restrict__ As, float* __restrict__ Ad,
                            float* __restrict__ cE)
{
    int t = threadIdx.x;          // 256 threads
    int i = t >> 2, hh = t & 3;   // t = i*4+hh
    float s = 0.f, d = 0.f;
    for (int j = 0; j < HID; j++){
        float w = W_gat[i*256 + hh*64 + j];
        s += w * att_src[hh*64 + j];
        d += w * att_dst[hh*64 + j];
    }
    As[t] = s;
    Ad[t] = d;
    if (t < 12){
        int e = t >> 2, h2 = t & 3;
        float cc = 0.f;
        for (int k = 0; k < HID; k++)
            cc += W_edge[e*256 + h2*64 + k] * att_edge[h2*64 + k];
        cE[h2*3 + e] = cc;
    }
}

// ---- encoder: block = 64 consecutive nodes, lane = node ----
__global__ __launch_bounds__(256) void enc_kernel(
    const float* __restrict__ x,
    const float* __restrict__ W1, const float* __restrict__ b1,
    const float* __restrict__ W2, const float* __restrict__ b2,
    const float* __restrict__ As, const float* __restrict__ Ad,
    float* __restrict__ H, float* __restrict__ HOUT,
    float* __restrict__ AS0, float* __restrict__ AD0)
{
    __shared__ float sm[7344];
    float* xT  = sm;          // [12][68]
    float* t1  = sm + 816;    // [64][68]
    float* pas = sm + 5168;   // [16][68]
    float* pad = sm + 6256;   // [16][68]

    int t = threadIdx.x;
    int w = __builtin_amdgcn_readfirstlane(t >> 6);
    int lane = t & 63;
    int n0 = blockIdx.x * 64;
    int b = n0 >> 12;
    int cell0 = n0 & 4095;

    for (int e = t; e < 12*64; e += 256){
        int c = e >> 6, u = e & 63;
        xT[c*68 + u] = x[b*(12*NN) + c*NN + cell0 + u];
    }
    __syncthreads();

    // layer 1: j-quarter per wave
    #pragma unroll
    for (int jj = 0; jj < 16; jj++){
        int j = w*16 + jj;
        float a = b1[j];
        #pragma unroll
        for (int c = 0; c < 12; c++)
            a += xT[c*68 + lane] * W1[c*64 + j];
        t1[j*68 + lane] = a * sigmoidf_(a);
    }
    __syncthreads();

    // layer 2: k-quarter per wave
    float hk[16];
    #pragma unroll
    for (int kk = 0; kk < 16; kk++) hk[kk] = b2[w*16 + kk];
    for (int j = 0; j < 64; j++){
        float v = t1[j*68 + lane];
        #pragma unroll
        for (int kk = 0; kk < 16; kk++)
            hk[kk] += v * W2[j*64 + w*16 + kk];
    }

    float pa[4] = {0,0,0,0}, pd[4] = {0,0,0,0};
    #pragma unroll
    for (int kk = 0; kk < 16; kk++){
        int k = w*16 + kk;
        int gi = k*BN + n0 + lane;
        H[gi]    = hk[kk];
        HOUT[gi] = hk[kk];
        #pragma unroll
        for (int hh = 0; hh < 4; hh++){
            pa[hh] += hk[kk] * As[k*4 + hh];
            pd[hh] += hk[kk] * Ad[k*4 + hh];
        }
    }
    #pragma unroll
    for (int hh = 0; hh < 4; hh++){
        pas[(w*4+hh)*68 + lane] = pa[hh];
        pad[(w*4+hh)*68 + lane] = pd[hh];
    }
    __syncthreads();
    {
        int hh = t >> 6;
        float sa = pas[(0*4+hh)*68+lane] + pas[(1*4+hh)*68+lane]
                 + pas[(2*4+hh)*68+lane] + pas[(3*4+hh)*68+lane];
        float sd = pad[(0*4+hh)*68+lane] + pad[(1*4+hh)*68+lane]
                 + pad[(2*4+hh)*68+lane] + pad[(3*4+hh)*68+lane];
        AS0[hh*BN + n0 + lane] = sa;
        AD0[hh*BN + n0 + lane] = sd;
    }
}

// ---- fused f(): stencil attention in h-space + GEMM + LN + silu + RK4 ----
// block = 8x8 spatial tile of one batch; 4 waves = 4 heads; lane = node in tile.
// HIN_in is read (incl. halo) and never written this launch; HIN_out written (own
// nodes only) -> no cross-block race (ping-pong buffers).
__global__ __launch_bounds__(256) void f_kernel(
    const float* __restrict__ HINc,      // stage input h [64][BN] (read-only)
    const float* __restrict__ ASi, const float* __restrict__ ADi,
    const float* __restrict__ x,  const float* __restrict__ cE,
    const float* __restrict__ Wg,
    const float* __restrict__ b_gat, const float* __restrict__ g_f, const float* __restrict__ bt_f,
    const float* __restrict__ As, const float* __restrict__ Ad,
    float* __restrict__ H, float* __restrict__ HOUT, float* __restrict__ ACC,
    float* __restrict__ ASo, float* __restrict__ ADo, int stage)
{
    __shared__ float sm[13184];
    float* hT   = sm;            // [64][128], halo rows pitch 12
    float* outl = sm + 8192;     // [64][68]
    float* ash  = sm + 12544;    // [4][128]
    float* x0h  = sm + 13056;    // [128]
    float* pasl = sm;            // alias hT (dead after gather)
    float* padl = sm + 2048;

    int t = threadIdx.x;
    int w = __builtin_amdgcn_readfirstlane(t >> 6);   // wave == head
    int lane = t & 63;
    int blk = blockIdx.x;
    int b = blk >> 6, tile = blk & 63;
    int tr = tile >> 3, tc = tile & 7;
    int r0 = tr*8 - 1, c0 = tc*8 - 1;   // halo origin
    int xb = b*(12*NN);
    int nb = b*NN;

    for (int e = t; e < 64*68; e += 256) outl[e] = 0.f;

    for (int e = t; e < 5*128; e += 256){
        int seg = e >> 7, u = e & 127;
        int hr = (u*171) >> 11;
        int hc = u - hr*12;
        if (hr < 10 && hc < 10){
            int r = min(63, max(0, r0 + hr));
            int c = min(63, max(0, c0 + hc));
            int g = r*64 + c;
            if (seg == 0) x0h[u] = x[xb + g];
            else          ash[(seg-1)*128 + u] = ASi[(seg-1)*BN + nb + g];
        }
    }
    for (int e = t; e < 64*128; e += 256){
        int kk = e >> 7, u = e & 127;
        int hr = (u*171) >> 11;
        int hc = u - hr*12;
        if (hr < 10 && hc < 10){
            int r = min(63, max(0, r0 + hr));
            int c = min(63, max(0, c0 + hc));
            hT[kk*128 + hr*12 + hc] = HINc[kk*BN + nb + r*64 + c];
        }
    }
    __syncthreads();

    // ---- per-(node,head) softmax over 8 stencil offsets (all in-thread) ----
    int i = lane >> 3, jc = lane & 7;
    int gr = tr*8 + i, gc = tc*8 + jc;
    int gn = nb + gr*64 + gc;
    int hcn = (i+1)*12 + (jc+1);
    float adv = ADi[w*BN + gn];
    float ce0 = cE[w*3+0], ce1 = cE[w*3+1], ce2 = cE[w*3+2];
    float x0n = x0h[hcn];

    float lg[8]; int hm[8];
    float mx = -1e30f;
    #pragma unroll
    for (int o = 0; o < 8; o++){
        const int dy = (o<3)? -1 : ((o<5)? 0 : 1);
        const int dx = (o<3)? (o-1) : ((o<5)? ((o==3)? -1 : 1) : (o-6));
        int mr = gr - dy, mc = gc - dx;
        bool v = (mr>=0)&&(mr<64)&&(mc>=0)&&(mc<64);
        int hmo = hcn - dy*12 - dx;
        float fdx = (float)dx, fdy = (float)dy;
        float inv = rsqrtf(fdx*fdx + fdy*fdy);
        float a = ash[w*128 + hmo] + adv
                + ce0*(fdx*inv) + ce1*(fdy*inv) + ce2*(x0n - x0h[hmo]);
        a = (a >= 0.f) ? a : 0.2f*a;
        lg[o] = v ? a : -1e30f;
        hm[o] = hmo;
        mx = fmaxf(mx, lg[o]);
    }
    float al[8]; float z = 0.f;
    #pragma unroll
    for (int o = 0; o < 8; o++){
        float p = (lg[o] > -1e29f) ? __expf(lg[o] - mx) : 0.f;
        al[o] = p; z += p;
    }
    float zin = 1.f / (z + 1e-16f);
    #pragma unroll
    for (int o = 0; o < 8; o++) al[o] *= zin;

    // ---- gather in h-space: G[k] = sum_o alpha_o * h[m_o][k] ----
    float G[64];
    #pragma unroll
    for (int k = 0; k < 64; k++) G[k] = 0.f;
    #pragma unroll
    for (int o = 0; o < 8; o++){
        float a = al[o];
        const float* hp = hT + hm[o];
        #pragma unroll
        for (int k = 0; k < 64; k++)
            G[k] += a * hp[k*128];
    }

    // ---- GEMM: partial out[j] for this head; W via uniform s_loads ----
    for (int pass = 0; pass < 4; pass++){
        float acc[16];
        #pragma unroll
        for (int jj = 0; jj < 16; jj++) acc[jj] = 0.f;
        #pragma unroll
        for (int k = 0; k < 64; k++){
            float g = G[k];
            const float* wp = Wg + k*256 + w*64 + pass*16;
            #pragma unroll
            for (int jj = 0; jj < 16; jj++)
                acc[jj] += g * wp[jj];
        }
        #pragma unroll
        for (int jj = 0; jj < 16; jj++)
            atomicAdd(&outl[(pass*16+jj)*68 + lane], acc[jj]);
    }
    __syncthreads();

    // ---- LN stats (per lane = node; redundant across waves) ----
    float s1 = 0.f, s2 = 0.f;
    for (int j = 0; j < 64; j++){
        float v = outl[j*68+lane]*0.25f + b_gat[j];
        s1 += v; s2 += v*v;
    }
    float mean = s1*(1.f/64.f);
    float var  = s2*(1.f/64.f) - mean*mean;
    float rstd = rsqrtf(fmaxf(var, 0.f) + 1e-5f);

    // ---- apply LN+silu+RK4 for this wave's j-quarter ----
    float hnext[16];
    #pragma unroll
    for (int jj = 0; jj < 16; jj++){
        int j = w*16 + jj;
        float v = outl[j*68+lane]*0.25f + b_gat[j];
        float y = (v - mean)*rstd*g_f[j] + bt_f[j];
        float kv = y * sigmoidf_(y);
        int gi = j*BN + gn;
        float hold = H[gi];
        float hn;
        if (stage == 0){ ACC[gi] = kv;              hn = hold + 0.125f*kv; }
        else if (stage == 1){ ACC[gi] += 2.f*kv;    hn = hold + 0.125f*kv; }
        else if (stage == 2){ ACC[gi] += 2.f*kv;    hn = hold + 0.25f*kv; }
        else { hn = hold + (0.25f/6.f)*(ACC[gi] + kv); H[gi] = hn; }
        HOUT[gi] = hn;
        hnext[jj] = hn;
    }

    // ---- epilogue: a_s/a_d of next-stage input ----
    float pa[4] = {0,0,0,0}, pd[4] = {0,0,0,0};
    #pragma unroll
    for (int jj = 0; jj < 16; jj++){
        int j = w*16 + jj;
        #pragma unroll
        for (int hh = 0; hh < 4; hh++){
            pa[hh] += hnext[jj] * As[j*4 + hh];
            pd[hh] += hnext[jj] * Ad[j*4 + hh];
        }
    }
    __syncthreads();   // everyone past gather/GEMM/LN -> hT region reusable
    #pragma unroll
    for (int hh = 0; hh < 4; hh++){
        pasl[(w*4+hh)*68 + lane] = pa[hh];
        padl[(w*4+hh)*68 + lane] = pd[hh];
    }
    __syncthreads();
    {
        int hh = t >> 6;
        float sa = pasl[(0*4+hh)*68+lane] + pasl[(1*4+hh)*68+lane]
                 + pasl[(2*4+hh)*68+lane] + pasl[(3*4+hh)*68+lane];
        float sd = padl[(0*4+hh)*68+lane] + padl[(1*4+hh)*68+lane]
                 + padl[(2*4+hh)*68+lane] + padl[(3*4+hh)*68+lane];
        ASo[hh*BN + gn] = sa;
        ADo[hh*BN + gn] = sd;
    }
}

// ---- head: LN + MLP + fire override. block = 64 consecutive nodes ----
__global__ __launch_bounds__(256) void head_kernel(
    const float* __restrict__ H, const float* __restrict__ x,
    const float* __restrict__ g_h, const float* __restrict__ bt_h,
    const float* __restrict__ Wh1, const float* __restrict__ bh1,
    const float* __restrict__ Wh2, const float* __restrict__ bh2,
    float* __restrict__ out)
{
    __shared__ float sm[4624];
    float* hT = sm;          // [64][68]
    float* pl = sm + 4352;   // [4][68]

    int t = threadIdx.x;
    int w = __builtin_amdgcn_readfirstlane(t >> 6);
    int lane = t & 63;
    int n0 = blockIdx.x * 64;
    int b = n0 >> 12;
    int cell0 = n0 & 4095;

    for (int e = t; e < 4096; e += 256){
        int j = e >> 6, u = e & 63;
        hT[j*68 + u] = H[j*BN + n0 + u];
    }
    __syncthreads();

    float s1 = 0.f, s2 = 0.f;
    for (int j = 0; j < 64; j++){
        float v = hT[j*68 + lane];
        s1 += v; s2 += v*v;
    }
    float mean = s1*(1.f/64.f);
    float var  = s2*(1.f/64.f) - mean*mean;
    float rstd = rsqrtf(fmaxf(var, 0.f) + 1e-5f);

    float acc[16];
    #pragma unroll
    for (int kk = 0; kk < 16; kk++) acc[kk] = bh1[w*16 + kk];
    for (int j = 0; j < 64; j++){
        float v = (hT[j*68 + lane] - mean)*rstd*g_h[j] + bt_h[j];
        #pragma unroll
        for (int kk = 0; kk < 16; kk++)
            acc[kk] += v * Wh1[j*64 + w*16 + kk];
    }
    float plg = 0.f;
    #pragma unroll
    for (int kk = 0; kk < 16; kk++){
        float a = acc[kk];
        plg += (a * sigmoidf_(a)) * Wh2[w*16 + kk];
    }
    pl[w*68 + lane] = plg;
    __syncthreads();
    if (t < 64){
        float lgt = pl[0*68+t] + pl[1*68+t] + pl[2*68+t] + pl[3*68+t] + bh2[0];
        float fire = x[b*(12*NN) + cell0 + t];
        out[n0 + t] = (fire > 0.5f) ? fmaxf(lgt, 6.f) : lgt;
    }
}

extern "C" void kernel_launch(void* const* d_in, const int* in_sizes, int n_in,
                              void* d_out, int out_size, void* d_ws, size_t ws_size,
                              hipStream_t stream)
{
    const float* x       = (const float*)d_in[0];
    const float* W_enc1  = (const float*)d_in[3];
    const float* b_enc1  = (const float*)d_in[4];
    const float* W_enc2  = (const float*)d_in[5];
    const float* b_enc2  = (const float*)d_in[6];
    const float* W_gat   = (const float*)d_in[7];
    const float* att_src = (const float*)d_in[8];
    const float* att_dst = (const float*)d_in[9];
    const float* W_edge  = (const float*)d_in[10];
    const float* att_edge= (const float*)d_in[11];
    const float* b_gat   = (const float*)d_in[12];
    const float* g_f     = (const float*)d_in[13];
    const float* bt_f    = (const float*)d_in[14];
    const float* g_h     = (const float*)d_in[15];
    const float* bt_h    = (const float*)d_in[16];
    const float* W_h1    = (const float*)d_in[17];
    const float* b_h1    = (const float*)d_in[18];
    const float* W_h2    = (const float*)d_in[19];
    const float* b_h2    = (const float*)d_in[20];

    float* ws  = (float*)d_ws;
    float* H   = ws;                 // [64][BN]
    float* HA  = ws + 2097152;       // [64][BN]  stage-input ping
    float* HB  = ws + 4194304;       // [64][BN]  stage-input pong
    float* ACC = ws + 6291456;       // [64][BN]
    float* AS0 = ws + 8388608;       // [4][BN]
    float* AD0 = ws + 8519680;
    float* AS1 = ws + 8650752;
    float* AD1 = ws + 8781824;
    float* CAS = ws + 8912896;       // 256
    float* CAD = ws + 8913152;       // 256
    float* CCE = ws + 8913408;       // 16
    float* out = (float*)d_out;

    prep_kernel<<<1, 256, 0, stream>>>(W_gat, att_src, att_dst, W_edge, att_edge, CAS, CAD, CCE);
    enc_kernel<<<512, 256, 0, stream>>>(x, W_enc1, b_enc1, W_enc2, b_enc2, CAS, CAD,
                                        H, HA, AS0, AD0);

    float* hin = HA; float* hout = HB;
    float* asi = AS0; float* adi = AD0;
    float* aso = AS1; float* ado = AD1;
    for (int step = 0; step < 4; step++){
        for (int st = 0; st < 4; st++){
            f_kernel<<<512, 256, 0, stream>>>(hin, asi, adi, x, CCE, W_gat,
                                              b_gat, g_f, bt_f, CAS, CAD,
                                              H, hout, ACC, aso, ado, st);
            float* tm;
            tm = hin; hin = hout; hout = tm;
            tm = asi; asi = aso; aso = tm;
            tm = adi; adi = ado; ado = tm;
        }
    }

    head_kernel<<<512, 256, 0, stream>>>(H, x, g_h, bt_h, W_h1, b_h1, W_h2, b_h2, out);
}

// Round 4
// 753.961 us; speedup vs baseline: 1.7691x; 1.7691x over previous
//
#include <hip/hip_runtime.h>

#define NN 4096
#define BB 8
#define BN 32768
#define HID 64

__device__ __forceinline__ float sigmoidf_(float x){ return 1.f / (1.f + __expf(-x)); }

// ---- tiny precompute: As[i*4+h], Ad[i*4+h], cE[h*3+e] ----
__global__ void prep_kernel(const float* __restrict__ W_gat,
                            const float* __restrict__ att_src,
                            const float* __restrict__ att_dst,
                            const float* __restrict__ W_edge,
                            const float* __restrict__ att_edge,
                            float* __restrict__ As, float* __restrict__ Ad,
                            float* __restrict__ cE)
{
    int t = threadIdx.x;          // 256 threads
    int i = t >> 2, hh = t & 3;   // t = i*4+hh
    float s = 0.f, d = 0.f;
    for (int j = 0; j < HID; j++){
        float w = W_gat[i*256 + hh*64 + j];
        s += w * att_src[hh*64 + j];
        d += w * att_dst[hh*64 + j];
    }
    As[t] = s;
    Ad[t] = d;
    if (t < 12){
        int e = t >> 2, h2 = t & 3;
        float cc = 0.f;
        for (int k = 0; k < HID; k++)
            cc += W_edge[e*256 + h2*64 + k] * att_edge[h2*64 + k];
        cE[h2*3 + e] = cc;
    }
}

// ---- encoder: block = 64 consecutive nodes, lane = node. node-major outputs ----
__global__ __launch_bounds__(256) void enc_kernel(
    const float* __restrict__ x,
    const float* __restrict__ W1, const float* __restrict__ b1,
    const float* __restrict__ W2, const float* __restrict__ b2,
    const float* __restrict__ As, const float* __restrict__ Ad,
    float* __restrict__ H, float* __restrict__ HOUT,
    float* __restrict__ AS0, float* __restrict__ AD0)
{
    __shared__ __align__(16) float sm[7344];
    float* xT  = sm;          // [12][68]
    float* t1  = sm + 816;    // [64][68]
    float* pas = sm + 5168;   // [16][68]
    float* pad = sm + 6256;   // [16][68]

    int t = threadIdx.x;
    int w = __builtin_amdgcn_readfirstlane(t >> 6);
    int lane = t & 63;
    int n0 = blockIdx.x * 64;
    int b = n0 >> 12;
    int cell0 = n0 & 4095;

    for (int e = t; e < 12*64; e += 256){
        int c = e >> 6, u = e & 63;
        xT[c*68 + u] = x[b*(12*NN) + c*NN + cell0 + u];
    }
    __syncthreads();

    // layer 1: j-quarter per wave
    #pragma unroll
    for (int jj = 0; jj < 16; jj++){
        int j = w*16 + jj;
        float a = b1[j];
        #pragma unroll
        for (int c = 0; c < 12; c++)
            a += xT[c*68 + lane] * W1[c*64 + j];
        t1[j*68 + lane] = a * sigmoidf_(a);
    }
    __syncthreads();

    // layer 2: k-quarter per wave
    float hk[16];
    #pragma unroll
    for (int kk = 0; kk < 16; kk++) hk[kk] = b2[w*16 + kk];
    for (int j = 0; j < 64; j++){
        float v = t1[j*68 + lane];
        #pragma unroll
        for (int kk = 0; kk < 16; kk++)
            hk[kk] += v * W2[j*64 + w*16 + kk];
    }

    // node-major stores: lane's 64B quarter-row = one cacheline
    int hb = (n0 + lane)*64 + w*16;
    #pragma unroll
    for (int j4 = 0; j4 < 4; j4++){
        float4 v = make_float4(hk[4*j4+0], hk[4*j4+1], hk[4*j4+2], hk[4*j4+3]);
        *(float4*)&H[hb + 4*j4]    = v;
        *(float4*)&HOUT[hb + 4*j4] = v;
    }

    float pa[4] = {0,0,0,0}, pd[4] = {0,0,0,0};
    #pragma unroll
    for (int kk = 0; kk < 16; kk++){
        int k = w*16 + kk;
        #pragma unroll
        for (int hh = 0; hh < 4; hh++){
            pa[hh] += hk[kk] * As[k*4 + hh];
            pd[hh] += hk[kk] * Ad[k*4 + hh];
        }
    }
    #pragma unroll
    for (int hh = 0; hh < 4; hh++){
        pas[(w*4+hh)*68 + lane] = pa[hh];
        pad[(w*4+hh)*68 + lane] = pd[hh];
    }
    __syncthreads();
    if (t < 64){
        float4 s;
        s.x = pas[(0*4+0)*68+t] + pas[(1*4+0)*68+t] + pas[(2*4+0)*68+t] + pas[(3*4+0)*68+t];
        s.y = pas[(0*4+1)*68+t] + pas[(1*4+1)*68+t] + pas[(2*4+1)*68+t] + pas[(3*4+1)*68+t];
        s.z = pas[(0*4+2)*68+t] + pas[(1*4+2)*68+t] + pas[(2*4+2)*68+t] + pas[(3*4+2)*68+t];
        s.w = pas[(0*4+3)*68+t] + pas[(1*4+3)*68+t] + pas[(2*4+3)*68+t] + pas[(3*4+3)*68+t];
        *(float4*)&AS0[(n0+t)*4] = s;
    } else if (t < 128){
        int u = t - 64;
        float4 s;
        s.x = pad[(0*4+0)*68+u] + pad[(1*4+0)*68+u] + pad[(2*4+0)*68+u] + pad[(3*4+0)*68+u];
        s.y = pad[(0*4+1)*68+u] + pad[(1*4+1)*68+u] + pad[(2*4+1)*68+u] + pad[(3*4+1)*68+u];
        s.z = pad[(0*4+2)*68+u] + pad[(1*4+2)*68+u] + pad[(2*4+2)*68+u] + pad[(3*4+2)*68+u];
        s.w = pad[(0*4+3)*68+u] + pad[(1*4+3)*68+u] + pad[(2*4+3)*68+u] + pad[(3*4+3)*68+u];
        *(float4*)&AD0[(n0+u)*4] = s;
    }
}

// ---- fused f(): node-major, stagger-reduced, 31KB LDS ----
// block = 8x8 spatial tile; 4 waves = 4 heads; lane = node in tile.
// grid swizzle: b = blk&7 (batch pinned to XCD), tile = blk>>3.
__global__ __launch_bounds__(256) void f_kernel(
    const float* __restrict__ HINc,      // stage input h [BN][64] (read-only)
    const float* __restrict__ ASi, const float* __restrict__ ADi,   // [BN][4]
    const float* __restrict__ x,  const float* __restrict__ cE,
    const float* __restrict__ Wg,
    const float* __restrict__ b_gat, const float* __restrict__ g_f, const float* __restrict__ bt_f,
    const float* __restrict__ As, const float* __restrict__ Ad,
    float* __restrict__ H, float* __restrict__ HOUT, float* __restrict__ ACC,
    float* __restrict__ ASo, float* __restrict__ ADo, int stage)
{
    __shared__ __align__(16) float sm[7816];
    float* hT   = sm;            // [100][68] halo node-major, pitch 68
    float* outl = sm;            // [64][64] alias (hT dead after gather)
    float* pasl = sm + 4096;     // [16][64] alias (beyond outl, within dead hT)
    float* padl = sm + 5120;     // [16][64]
    float* ASh  = sm + 6800;     // [100][4]
    float* x0h  = sm + 7200;     // [100]+pad
    float* s1p  = sm + 7304;     // [4][64]
    float* s2p  = sm + 7560;     // [4][64]

    int t = threadIdx.x;
    int w = __builtin_amdgcn_readfirstlane(t >> 6);   // wave == head
    int lane = t & 63;
    int blk = blockIdx.x;
    int b = blk & 7, tile = blk >> 3;      // XCD-pinned batch
    int tr = tile >> 3, tc = tile & 7;
    int r0 = tr*8 - 1, c0 = tc*8 - 1;      // halo origin
    int xb = b*(12*NN);
    int nb = b*NN;

    // ---- stage halo: x0 + AS (100 nodes), h (100 nodes x 64, float4) ----
    for (int m = t; m < 100; m += 256){
        int hr = m/10, hc = m - hr*10;
        int r = min(63, max(0, r0 + hr));
        int c = min(63, max(0, c0 + hc));
        int g = r*64 + c;
        x0h[m] = x[xb + g];
        *(float4*)&ASh[m*4] = *(const float4*)&ASi[(nb + g)*4];
    }
    for (int e = t; e < 1600; e += 256){
        int m = e >> 4, k4 = e & 15;
        int hr = m/10, hc = m - hr*10;
        int r = min(63, max(0, r0 + hr));
        int c = min(63, max(0, c0 + hc));
        *(float4*)&hT[m*68 + 4*k4] =
            *(const float4*)&HINc[(nb + r*64 + c)*64 + 4*k4];
    }
    __syncthreads();

    // ---- per-(node,head) softmax over 8 stencil offsets ----
    int i = lane >> 3, jc = lane & 7;
    int gr = tr*8 + i, gc = tc*8 + jc;
    int gn = nb + gr*64 + gc;
    int own = (i+1)*10 + (jc+1);
    float adv = ADi[gn*4 + w];
    float ce0 = cE[w*3+0], ce1 = cE[w*3+1], ce2 = cE[w*3+2];
    float x0n = x0h[own];

    float al[8]; int hm[8];
    float mx = -1e30f;
    #pragma unroll
    for (int o = 0; o < 8; o++){
        const int dy = (o<3)? -1 : ((o<5)? 0 : 1);
        const int dx = (o<3)? (o-1) : ((o<5)? ((o==3)? -1 : 1) : (o-6));
        int mr = gr - dy, mc = gc - dx;
        bool v = (mr>=0)&&(mr<64)&&(mc>=0)&&(mc<64);
        int hmo = own - dy*10 - dx;
        float fdx = (float)dx, fdy = (float)dy;
        float inv = rsqrtf(fdx*fdx + fdy*fdy);
        float a = ASh[hmo*4 + w] + adv
                + ce0*(fdx*inv) + ce1*(fdy*inv) + ce2*(x0n - x0h[hmo]);
        a = (a >= 0.f) ? a : 0.2f*a;
        al[o] = v ? a : -1e30f;
        hm[o] = hmo;
        mx = fmaxf(mx, al[o]);
    }
    float z = 0.f;
    #pragma unroll
    for (int o = 0; o < 8; o++){
        float p = (al[o] > -1e29f) ? __expf(al[o] - mx) : 0.f;
        al[o] = p; z += p;
    }
    float zin = 1.f / (z + 1e-16f);
    #pragma unroll
    for (int o = 0; o < 8; o++) al[o] *= zin;

    // ---- gather in h-space: G[k] = sum_o alpha_o * h[m_o][k]  (float4 LDS reads) ----
    float G[64];
    #pragma unroll
    for (int k = 0; k < 64; k++) G[k] = 0.f;
    #pragma unroll
    for (int o = 0; o < 8; o++){
        float a = al[o];
        const float* hp = hT + hm[o]*68;
        #pragma unroll
        for (int k4 = 0; k4 < 16; k4++){
            float4 v = *(const float4*)&hp[4*k4];
            G[4*k4+0] += a*v.x; G[4*k4+1] += a*v.y;
            G[4*k4+2] += a*v.z; G[4*k4+3] += a*v.w;
        }
    }
    __syncthreads();           // hT dead; outl region reusable

    // ---- zero outl, then head-staggered accumulation (no atomics) ----
    for (int e = t; e < 4096; e += 256) outl[e] = 0.f;
    __syncthreads();

    for (int p = 0; p < 4; p++){
        int q = (w + p) & 3;
        float acc[16];
        #pragma unroll
        for (int jj = 0; jj < 16; jj++) acc[jj] = 0.f;
        #pragma unroll 8
        for (int k = 0; k < 64; k++){
            float g = G[k];
            const float* wp = Wg + k*256 + w*64 + q*16;
            #pragma unroll
            for (int jj = 0; jj < 16; jj++)
                acc[jj] += g * wp[jj];
        }
        #pragma unroll
        for (int jj = 0; jj < 16; jj++)
            outl[(q*16+jj)*64 + lane] += acc[jj];
        __syncthreads();
    }

    // ---- LN stats via per-wave partials ----
    {
        float s1 = 0.f, s2 = 0.f;
        #pragma unroll
        for (int jj = 0; jj < 16; jj++){
            float v = outl[(w*16+jj)*64 + lane]*0.25f + b_gat[w*16+jj];
            s1 += v; s2 += v*v;
        }
        s1p[w*64 + lane] = s1;
        s2p[w*64 + lane] = s2;
    }
    __syncthreads();
    float s1 = s1p[lane] + s1p[64+lane] + s1p[128+lane] + s1p[192+lane];
    float s2 = s2p[lane] + s2p[64+lane] + s2p[128+lane] + s2p[192+lane];
    float mean = s1*(1.f/64.f);
    float var  = s2*(1.f/64.f) - mean*mean;
    float rstd = rsqrtf(fmaxf(var, 0.f) + 1e-5f);

    // ---- LN+silu+RK4 for this wave's j-quarter (vectorized state I/O) ----
    int hb = gn*64 + w*16;
    float hold[16], av[16], kvv[16], hnext[16];
    #pragma unroll
    for (int j4 = 0; j4 < 4; j4++)
        *(float4*)&hold[4*j4] = *(const float4*)&H[hb + 4*j4];
    if (stage > 0){
        #pragma unroll
        for (int j4 = 0; j4 < 4; j4++)
            *(float4*)&av[4*j4] = *(const float4*)&ACC[hb + 4*j4];
    }
    #pragma unroll
    for (int jj = 0; jj < 16; jj++){
        int j = w*16 + jj;
        float v = outl[j*64 + lane]*0.25f + b_gat[j];
        float y = (v - mean)*rstd*g_f[j] + bt_f[j];
        kvv[jj] = y * sigmoidf_(y);
    }
    if (stage == 0){
        #pragma unroll
        for (int jj = 0; jj < 16; jj++){ av[jj] = kvv[jj]; hnext[jj] = hold[jj] + 0.125f*kvv[jj]; }
    } else if (stage == 1){
        #pragma unroll
        for (int jj = 0; jj < 16; jj++){ av[jj] += 2.f*kvv[jj]; hnext[jj] = hold[jj] + 0.125f*kvv[jj]; }
    } else if (stage == 2){
        #pragma unroll
        for (int jj = 0; jj < 16; jj++){ av[jj] += 2.f*kvv[jj]; hnext[jj] = hold[jj] + 0.25f*kvv[jj]; }
    } else {
        #pragma unroll
        for (int jj = 0; jj < 16; jj++){ hnext[jj] = hold[jj] + (0.25f/6.f)*(av[jj] + kvv[jj]); }
    }
    #pragma unroll
    for (int j4 = 0; j4 < 4; j4++){
        *(float4*)&HOUT[hb + 4*j4] = *(float4*)&hnext[4*j4];
        if (stage < 3) *(float4*)&ACC[hb + 4*j4] = *(float4*)&av[4*j4];
        else           *(float4*)&H[hb + 4*j4]   = *(float4*)&hnext[4*j4];
    }

    // ---- epilogue: a_s/a_d of next-stage input ----
    float pa[4] = {0,0,0,0}, pd[4] = {0,0,0,0};
    #pragma unroll
    for (int jj = 0; jj < 16; jj++){
        int j = w*16 + jj;
        #pragma unroll
        for (int hh = 0; hh < 4; hh++){
            pa[hh] += hnext[jj] * As[j*4 + hh];
            pd[hh] += hnext[jj] * Ad[j*4 + hh];
        }
    }
    #pragma unroll
    for (int hh = 0; hh < 4; hh++){
        pasl[(w*4+hh)*64 + lane] = pa[hh];
        padl[(w*4+hh)*64 + lane] = pd[hh];
    }
    __syncthreads();
    if (t < 64){
        int ii = t >> 3, jj2 = t & 7;
        int g2 = nb + (tr*8+ii)*64 + tc*8 + jj2;
        float4 s;
        s.x = pasl[0*64+t] + pasl[4*64+t] + pasl[8*64+t]  + pasl[12*64+t];
        s.y = pasl[1*64+t] + pasl[5*64+t] + pasl[9*64+t]  + pasl[13*64+t];
        s.z = pasl[2*64+t] + pasl[6*64+t] + pasl[10*64+t] + pasl[14*64+t];
        s.w = pasl[3*64+t] + pasl[7*64+t] + pasl[11*64+t] + pasl[15*64+t];
        *(float4*)&ASo[g2*4] = s;
    } else if (t < 128){
        int u = t - 64;
        int ii = u >> 3, jj2 = u & 7;
        int g2 = nb + (tr*8+ii)*64 + tc*8 + jj2;
        float4 s;
        s.x = padl[0*64+u] + padl[4*64+u] + padl[8*64+u]  + padl[12*64+u];
        s.y = padl[1*64+u] + padl[5*64+u] + padl[9*64+u]  + padl[13*64+u];
        s.z = padl[2*64+u] + padl[6*64+u] + padl[10*64+u] + padl[14*64+u];
        s.w = padl[3*64+u] + padl[7*64+u] + padl[11*64+u] + padl[15*64+u];
        *(float4*)&ADo[g2*4] = s;
    }
}

// ---- head: LN + MLP + fire override. block = 64 consecutive nodes ----
__global__ __launch_bounds__(256) void head_kernel(
    const float* __restrict__ H, const float* __restrict__ x,
    const float* __restrict__ g_h, const float* __restrict__ bt_h,
    const float* __restrict__ Wh1, const float* __restrict__ bh1,
    const float* __restrict__ Wh2, const float* __restrict__ bh2,
    float* __restrict__ out)
{
    __shared__ __align__(16) float sm[4624];
    float* hT = sm;          // [64 dims][68] dim-major (transposed at stage)
    float* pl = sm + 4352;   // [4][68]

    int t = threadIdx.x;
    int w = __builtin_amdgcn_readfirstlane(t >> 6);
    int lane = t & 63;
    int n0 = blockIdx.x * 64;
    int b = n0 >> 12;
    int cell0 = n0 & 4095;

    for (int e = t; e < 4096; e += 256){
        int n = e >> 6, j = e & 63;
        hT[j*68 + n] = H[(n0+n)*64 + j];
    }
    __syncthreads();

    float s1 = 0.f, s2 = 0.f;
    for (int j = 0; j < 64; j++){
        float v = hT[j*68 + lane];
        s1 += v; s2 += v*v;
    }
    float mean = s1*(1.f/64.f);
    float var  = s2*(1.f/64.f) - mean*mean;
    float rstd = rsqrtf(fmaxf(var, 0.f) + 1e-5f);

    float acc[16];
    #pragma unroll
    for (int kk = 0; kk < 16; kk++) acc[kk] = bh1[w*16 + kk];
    for (int j = 0; j < 64; j++){
        float v = (hT[j*68 + lane] - mean)*rstd*g_h[j] + bt_h[j];
        #pragma unroll
        for (int kk = 0; kk < 16; kk++)
            acc[kk] += v * Wh1[j*64 + w*16 + kk];
    }
    float plg = 0.f;
    #pragma unroll
    for (int kk = 0; kk < 16; kk++){
        float a = acc[kk];
        plg += (a * sigmoidf_(a)) * Wh2[w*16 + kk];
    }
    pl[w*68 + lane] = plg;
    __syncthreads();
    if (t < 64){
        float lgt = pl[0*68+t] + pl[1*68+t] + pl[2*68+t] + pl[3*68+t] + bh2[0];
        float fire = x[b*(12*NN) + cell0 + t];
        out[n0 + t] = (fire > 0.5f) ? fmaxf(lgt, 6.f) : lgt;
    }
}

extern "C" void kernel_launch(void* const* d_in, const int* in_sizes, int n_in,
                              void* d_out, int out_size, void* d_ws, size_t ws_size,
                              hipStream_t stream)
{
    const float* x       = (const float*)d_in[0];
    const float* W_enc1  = (const float*)d_in[3];
    const float* b_enc1  = (const float*)d_in[4];
    const float* W_enc2  = (const float*)d_in[5];
    const float* b_enc2  = (const float*)d_in[6];
    const float* W_gat   = (const float*)d_in[7];
    const float* att_src = (const float*)d_in[8];
    const float* att_dst = (const float*)d_in[9];
    const float* W_edge  = (const float*)d_in[10];
    const float* att_edge= (const float*)d_in[11];
    const float* b_gat   = (const float*)d_in[12];
    const float* g_f     = (const float*)d_in[13];
    const float* bt_f    = (const float*)d_in[14];
    const float* g_h     = (const float*)d_in[15];
    const float* bt_h    = (const float*)d_in[16];
    const float* W_h1    = (const float*)d_in[17];
    const float* b_h1    = (const float*)d_in[18];
    const float* W_h2    = (const float*)d_in[19];
    const float* b_h2    = (const float*)d_in[20];

    float* ws  = (float*)d_ws;
    float* H   = ws;                 // [BN][64]
    float* HA  = ws + 2097152;       // [BN][64]  stage-input ping
    float* HB  = ws + 4194304;       // [BN][64]  stage-input pong
    float* ACC = ws + 6291456;       // [BN][64]
    float* AS0 = ws + 8388608;       // [BN][4]
    float* AD0 = ws + 8519680;
    float* AS1 = ws + 8650752;
    float* AD1 = ws + 8781824;
    float* CAS = ws + 8912896;       // 256
    float* CAD = ws + 8913152;       // 256
    float* CCE = ws + 8913408;       // 16
    float* out = (float*)d_out;

    prep_kernel<<<1, 256, 0, stream>>>(W_gat, att_src, att_dst, W_edge, att_edge, CAS, CAD, CCE);
    enc_kernel<<<512, 256, 0, stream>>>(x, W_enc1, b_enc1, W_enc2, b_enc2, CAS, CAD,
                                        H, HA, AS0, AD0);

    float* hin = HA; float* hout = HB;
    float* asi = AS0; float* adi = AD0;
    float* aso = AS1; float* ado = AD1;
    for (int step = 0; step < 4; step++){
        for (int st = 0; st < 4; st++){
            f_kernel<<<512, 256, 0, stream>>>(hin, asi, adi, x, CCE, W_gat,
                                              b_gat, g_f, bt_f, CAS, CAD,
                                              H, hout, ACC, aso, ado, st);
            float* tm;
            tm = hin; hin = hout; hout = tm;
            tm = asi; asi = aso; aso = tm;
            tm = adi; adi = ado; ado = tm;
        }
    }

    head_kernel<<<512, 256, 0, stream>>>(H, x, g_h, bt_h, W_h1, b_h1, W_h2, b_h2, out);
}

// Round 5
// 484.532 us; speedup vs baseline: 2.7528x; 1.5561x over previous
//
#include <hip/hip_runtime.h>

#define NN 4096
#define BN 32768

typedef __attribute__((ext_vector_type(8))) short short8;
typedef __attribute__((ext_vector_type(4))) float f32x4;

__device__ __forceinline__ float sigmoidf_(float x){ return 1.f/(1.f+__expf(-x)); }
__device__ __forceinline__ unsigned short bfr(float f){
    unsigned int u = __float_as_uint(f);
    u += 0x7FFFu + ((u>>16)&1u);
    return (unsigned short)(u>>16);
}
__device__ __forceinline__ float b2f(unsigned short h){
    return __uint_as_float(((unsigned int)h)<<16);
}

// ---- precompute: As[k*4+h], Ad[k*4+h], cE[h*3+e], WgT hi/lo bf16 [256][64] ----
__global__ void prep_kernel(const float* __restrict__ W_gat,
                            const float* __restrict__ att_src,
                            const float* __restrict__ att_dst,
                            const float* __restrict__ W_edge,
                            const float* __restrict__ att_edge,
                            float* __restrict__ As, float* __restrict__ Ad,
                            float* __restrict__ cE,
                            unsigned short* __restrict__ WgTh,
                            unsigned short* __restrict__ WgTl)
{
    int t = threadIdx.x;          // 256 threads
    int i = t >> 2, hh = t & 3;   // t = k*4+h
    float s = 0.f, d = 0.f;
    for (int j = 0; j < 64; j++){
        float w = W_gat[i*256 + hh*64 + j];
        s += w * att_src[hh*64 + j];
        d += w * att_dst[hh*64 + j];
    }
    As[t] = s;
    Ad[t] = d;
    if (t < 12){
        int e = t >> 2, h2 = t & 3;
        float cc = 0.f;
        for (int k = 0; k < 64; k++)
            cc += W_edge[e*256 + h2*64 + k] * att_edge[h2*64 + k];
        cE[h2*3 + e] = cc;
    }
    // transpose W_gat -> [n][k] bf16 hi/lo
    for (int k = 0; k < 64; k++){
        float wv = W_gat[k*256 + t];
        unsigned short hi = bfr(wv);
        WgTh[t*64 + k] = hi;
        WgTl[t*64 + k] = bfr(wv - b2f(hi));
    }
}

// ---- encoder: block = 64 consecutive nodes, lane = node; node-major H ----
__global__ __launch_bounds__(256) void enc_kernel(
    const float* __restrict__ x,
    const float* __restrict__ W1, const float* __restrict__ b1,
    const float* __restrict__ W2, const float* __restrict__ b2,
    float* __restrict__ H)
{
    __shared__ __align__(16) float sm[5168];
    float* xT  = sm;          // [12][68]
    float* t1  = sm + 816;    // [64][68]

    int t = threadIdx.x;
    int w = __builtin_amdgcn_readfirstlane(t >> 6);
    int lane = t & 63;
    int n0 = blockIdx.x * 64;
    int b = n0 >> 12;
    int cell0 = n0 & 4095;

    for (int e = t; e < 12*64; e += 256){
        int c = e >> 6, u = e & 63;
        xT[c*68 + u] = x[b*(12*NN) + c*NN + cell0 + u];
    }
    __syncthreads();

    #pragma unroll
    for (int jj = 0; jj < 16; jj++){
        int j = w*16 + jj;
        float a = b1[j];
        #pragma unroll
        for (int c = 0; c < 12; c++)
            a += xT[c*68 + lane] * W1[c*64 + j];
        t1[j*68 + lane] = a * sigmoidf_(a);
    }
    __syncthreads();

    float hk[16];
    #pragma unroll
    for (int kk = 0; kk < 16; kk++) hk[kk] = b2[w*16 + kk];
    for (int j = 0; j < 64; j++){
        float v = t1[j*68 + lane];
        #pragma unroll
        for (int kk = 0; kk < 16; kk++)
            hk[kk] += v * W2[j*64 + w*16 + kk];
    }
    int hb = (n0 + lane)*64 + w*16;
    #pragma unroll
    for (int j4 = 0; j4 < 4; j4++)
        *(float4*)&H[hb + 4*j4] = make_float4(hk[4*j4+0], hk[4*j4+1], hk[4*j4+2], hk[4*j4+3]);
}

// ================= fused 2-stage f() =================
// block = 8x8 tile + halo-2 (12x12); 4 waves; PAIR 0 = (k1,k2), PAIR 1 = (k3,k4)
template<int PAIR, bool ISA>
__device__ __forceinline__ void run_stage(
    int t, int w, int lane, int tr, int tc, int b,
    unsigned short* hA, unsigned short* xlb, unsigned short* alh,
    float* as2, float* ad2, const float* x0h, float* kA, float* s1p, float* s2p,
    const float* cE, const float* As, const float* Ad,
    const unsigned short* WgTh, const unsigned short* WgTl,
    const float* b_gat, const float* g_f, const float* bt_f,
    const float* Hc, float* ACC, float* OUT)
{
    const int nb = b*NN;
    const int r0 = tr*8 - 2, c0 = tc*8 - 2;
    const int NIT = ISA ? 2 : 1;
    const int NEV = ISA ? 100 : 64;
    const float s2c = 0.70710678f;
    const int DYI[8] = {-1,-1,-1,0,0,1,1,1};
    const int DXI[8] = {-1,0,1,-1,1,-1,0,1};
    const float DXN[8] = {-s2c,0.f,s2c,-1.f,1.f,-s2c,0.f,s2c};
    const float DYN[8] = {-s2c,-1.f,-s2c,0.f,0.f,s2c,1.f,s2c};

    // ---- a_s/a_d from current hA (folded with x0 terms) ----
    if (t < 144){
        float pa0=0,pa1=0,pa2=0,pa3=0, pd0=0,pd1=0,pd2=0,pd3=0;
        for (int k0 = 0; k0 < 64; k0 += 8){
            short8 hv = *(const short8*)&hA[t*72 + k0];
            #pragma unroll
            for (int i = 0; i < 8; i++){
                float hf = b2f((unsigned short)hv[i]);
                const float* asp = &As[(k0+i)*4];
                const float* adp = &Ad[(k0+i)*4];
                pa0 += hf*asp[0]; pa1 += hf*asp[1]; pa2 += hf*asp[2]; pa3 += hf*asp[3];
                pd0 += hf*adp[0]; pd1 += hf*adp[1]; pd2 += hf*adp[2]; pd3 += hf*adp[3];
            }
        }
        float xv = x0h[t];
        as2[t*4+0] = pa0 - cE[2]*xv;  as2[t*4+1] = pa1 - cE[5]*xv;
        as2[t*4+2] = pa2 - cE[8]*xv;  as2[t*4+3] = pa3 - cE[11]*xv;
        ad2[t*4+0] = pd0 + cE[2]*xv;  ad2[t*4+1] = pd1 + cE[5]*xv;
        ad2[t*4+2] = pd2 + cE[8]*xv;  ad2[t*4+3] = pd3 + cE[11]*xv;
    }
    __syncthreads();

    // ---- alpha for head w ----
    {
        float ce0 = cE[w*3+0], ce1 = cE[w*3+1];
        #pragma unroll
        for (int it = 0; it < NIT; ++it){
            int v = it*64 + lane;
            if (v < NEV){
                int hr, hc;
                if (ISA){ int vr = v/10; hr = vr + 1; hc = v - vr*10 + 1; }
                else    { hr = (lane>>3) + 2; hc = (lane&7) + 2; }
                int gr = r0 + hr, gc = c0 + hc;
                float adv = ad2[(hr*12+hc)*4 + w];
                float lg[8]; float mx = -1e30f;
                #pragma unroll
                for (int o = 0; o < 8; o++){
                    int mr = gr - DYI[o], mc = gc - DXI[o];
                    bool valid = (mr>=0)&&(mr<64)&&(mc>=0)&&(mc<64);
                    int hm = (hr-DYI[o])*12 + (hc-DXI[o]);
                    float a = as2[hm*4+w] + adv + ce0*DXN[o] + ce1*DYN[o];
                    a = (a >= 0.f) ? a : 0.2f*a;
                    lg[o] = valid ? a : -1e30f;
                    mx = fmaxf(mx, lg[o]);
                }
                float al[8]; float z = 0.f;
                #pragma unroll
                for (int o = 0; o < 8; o++){
                    float p = (lg[o] > -1e29f) ? __expf(lg[o]-mx) : 0.f;
                    al[o] = p; z += p;
                }
                float zi = 1.f/(z + 1e-16f);
                unsigned int u0 = (unsigned int)bfr(al[0]*zi) | ((unsigned int)bfr(al[1]*zi)<<16);
                unsigned int u1 = (unsigned int)bfr(al[2]*zi) | ((unsigned int)bfr(al[3]*zi)<<16);
                unsigned int u2 = (unsigned int)bfr(al[4]*zi) | ((unsigned int)bfr(al[5]*zi)<<16);
                unsigned int u3 = (unsigned int)bfr(al[6]*zi) | ((unsigned int)bfr(al[7]*zi)<<16);
                unsigned int* ap = (unsigned int*)&alh[(w*112 + v)*12];
                ap[0]=u0; ap[1]=u1; ap[2]=u2; ap[3]=u3;
            }
        }
    }
    __syncthreads();

    // ---- per-head: MFMA xl (bf16, W hi/lo split) then alpha-combine ----
    float outR[2][16];
    #pragma unroll
    for (int it = 0; it < 2; ++it)
        #pragma unroll
        for (int i = 0; i < 16; i++) outR[it][i] = 0.f;

    for (int q = 0; q < 4; ++q){
        {
            int l15 = lane & 15, kg = (lane>>4)*8;
            for (int mt = w; mt < 9; mt += 4){
                int arow = mt*16 + l15;
                short8 a0 = *(const short8*)&hA[arow*72 + kg];
                short8 a1 = *(const short8*)&hA[arow*72 + 32 + kg];
                #pragma unroll
                for (int nt = 0; nt < 4; ++nt){
                    int col = q*64 + nt*16 + l15;
                    short8 bh0 = *(const short8*)&WgTh[col*64 + kg];
                    short8 bh1 = *(const short8*)&WgTh[col*64 + 32 + kg];
                    short8 bl0 = *(const short8*)&WgTl[col*64 + kg];
                    short8 bl1 = *(const short8*)&WgTl[col*64 + 32 + kg];
                    f32x4 acc = {0.f,0.f,0.f,0.f};
                    acc = __builtin_amdgcn_mfma_f32_16x16x32_bf16(a0,bh0,acc,0,0,0);
                    acc = __builtin_amdgcn_mfma_f32_16x16x32_bf16(a1,bh1,acc,0,0,0);
                    acc = __builtin_amdgcn_mfma_f32_16x16x32_bf16(a0,bl0,acc,0,0,0);
                    acc = __builtin_amdgcn_mfma_f32_16x16x32_bf16(a1,bl1,acc,0,0,0);
                    int crow = mt*16 + (lane>>4)*4;
                    int ccol = nt*16 + l15;
                    xlb[(crow+0)*72 + ccol] = bfr(acc[0]);
                    xlb[(crow+1)*72 + ccol] = bfr(acc[1]);
                    xlb[(crow+2)*72 + ccol] = bfr(acc[2]);
                    xlb[(crow+3)*72 + ccol] = bfr(acc[3]);
                }
            }
        }
        __syncthreads();
        #pragma unroll
        for (int it = 0; it < NIT; ++it){
            int v = it*64 + lane;
            if (v < NEV){
                int hr, hc;
                if (ISA){ int vr = v/10; hr = vr + 1; hc = v - vr*10 + 1; }
                else    { hr = (lane>>3) + 2; hc = (lane&7) + 2; }
                const unsigned int* ap = (const unsigned int*)&alh[(q*112 + v)*12];
                unsigned int u0=ap[0], u1=ap[1], u2=ap[2], u3=ap[3];
                float al[8];
                al[0]=b2f((unsigned short)(u0&0xFFFFu)); al[1]=b2f((unsigned short)(u0>>16));
                al[2]=b2f((unsigned short)(u1&0xFFFFu)); al[3]=b2f((unsigned short)(u1>>16));
                al[4]=b2f((unsigned short)(u2&0xFFFFu)); al[5]=b2f((unsigned short)(u2>>16));
                al[6]=b2f((unsigned short)(u3&0xFFFFu)); al[7]=b2f((unsigned short)(u3>>16));
                #pragma unroll
                for (int o = 0; o < 8; o++){
                    int hm = (hr-DYI[o])*12 + (hc-DXI[o]);
                    float a = al[o];
                    short8 xv0 = *(const short8*)&xlb[hm*72 + w*16];
                    short8 xv1 = *(const short8*)&xlb[hm*72 + w*16 + 8];
                    #pragma unroll
                    for (int i = 0; i < 8; i++){
                        outR[it][i]   += a * b2f((unsigned short)xv0[i]);
                        outR[it][8+i] += a * b2f((unsigned short)xv1[i]);
                    }
                }
            }
        }
        __syncthreads();
    }

    // ---- epilogue: LN + silu + stage update ----
    #pragma unroll
    for (int it = 0; it < NIT; ++it){
        int v = it*64 + lane;
        bool act = v < NEV;
        int hr = 2, hc = 2;
        if (ISA){ if (act){ int vr = v/10; hr = vr + 1; hc = v - vr*10 + 1; } }
        else { hr = (lane>>3) + 2; hc = (lane&7) + 2; }
        float vv[16];
        float s1 = 0.f, s2 = 0.f;
        if (act){
            #pragma unroll
            for (int i = 0; i < 16; i++){
                float y = outR[it][i]*0.25f + b_gat[w*16+i];
                vv[i] = y; s1 += y; s2 += y*y;
            }
        }
        s1p[w*64+lane] = s1; s2p[w*64+lane] = s2;
        __syncthreads();
        if (act){
            float S1 = s1p[lane]+s1p[64+lane]+s1p[128+lane]+s1p[192+lane];
            float S2 = s2p[lane]+s2p[64+lane]+s2p[128+lane]+s2p[192+lane];
            float mean = S1*(1.f/64.f);
            float var  = S2*(1.f/64.f) - mean*mean;
            float rstd = rsqrtf(fmaxf(var,0.f) + 1e-5f);
            if (ISA){
                int m = hr*12 + hc;
                int gr = r0 + hr, gc = c0 + hc;
                int grc = min(63,max(0,gr)), gcc = min(63,max(0,gc));
                const float* hcp = &Hc[(long)(nb + grc*64 + gcc)*64 + w*16];
                int vr = hr - 1, vc = hc - 1;
                bool own = (vr>=1)&&(vr<9)&&(vc>=1)&&(vc<9);
                int oidx = (vr-1)*8 + (vc-1);
                #pragma unroll
                for (int i = 0; i < 16; i++){
                    float y = (vv[i]-mean)*rstd*g_f[w*16+i] + bt_f[w*16+i];
                    float kk = y * sigmoidf_(y);
                    float hb;
                    if (PAIR == 0) hb = b2f(hA[m*72 + w*16 + i]);
                    else           hb = hcp[i];
                    float hmid = hb + (PAIR==0 ? 0.125f : 0.25f)*kk;
                    hA[m*72 + w*16 + i] = bfr(hmid);
                    if (own) kA[oidx*72 + w*16 + i] = kk;
                }
            } else {
                int r = lane>>3, c = lane&7;
                long gn = nb + (tr*8+r)*64 + (tc*8+c);
                const float* hcp  = &Hc[gn*64 + w*16];
                float* accp = &ACC[gn*64 + w*16];
                float* outp = &OUT[gn*64 + w*16];
                #pragma unroll
                for (int i = 0; i < 16; i++){
                    float y = (vv[i]-mean)*rstd*g_f[w*16+i] + bt_f[w*16+i];
                    float kk = y * sigmoidf_(y);
                    float kav = kA[lane*72 + w*16 + i];
                    if (PAIR == 0){
                        accp[i] = kav + 2.f*kk;
                        outp[i] = hcp[i] + 0.125f*kk;
                    } else {
                        outp[i] = hcp[i] + (accp[i] + 2.f*kav + kk)*(1.f/24.f);
                    }
                }
            }
        }
        __syncthreads();
    }
}

template<int PAIR>
__global__ __launch_bounds__(256) void f2_kernel(
    const float* __restrict__ HIN, const float* __restrict__ Hc,
    const float* __restrict__ x,
    const float* __restrict__ cE, const float* __restrict__ As, const float* __restrict__ Ad,
    const unsigned short* __restrict__ WgTh, const unsigned short* __restrict__ WgTl,
    const float* __restrict__ b_gat, const float* __restrict__ g_f, const float* __restrict__ bt_f,
    float* __restrict__ ACC, float* __restrict__ OUT)
{
    __shared__ __align__(16) char smem[77888];
    unsigned short* hA  = (unsigned short*)(smem);           // [144][72] bf16
    unsigned short* xlb = (unsigned short*)(smem + 20736);   // [144][72] bf16
    unsigned short* alh = (unsigned short*)(smem + 41472);   // [4][112][12] bf16
    float* as2 = (float*)(smem + 52224);                     // [144][4]
    float* ad2 = (float*)(smem + 54528);                     // [144][4]
    float* x0h = (float*)(smem + 56832);                     // [144]
    float* kA  = (float*)(smem + 57408);                     // [64][72]
    float* s1p = (float*)(smem + 75840);                     // [4][64]
    float* s2p = (float*)(smem + 76864);                     // [4][64]

    int t = threadIdx.x;
    int w = __builtin_amdgcn_readfirstlane(t >> 6);
    int lane = t & 63;
    int blk = blockIdx.x;
    int b = blk & 7, tile = blk >> 3;    // batch pinned to XCD
    int tr = tile >> 3, tc = tile & 7;
    int r0 = tr*8 - 2, c0 = tc*8 - 2;
    int nb = b*NN;
    int xb = b*(12*NN);

    for (int m = t; m < 144; m += 256){
        int hr = m/12, hc = m - (m/12)*12;
        int r = min(63,max(0,r0+hr)), c = min(63,max(0,c0+hc));
        x0h[m] = x[xb + r*64 + c];
    }
    for (int e = t; e < 2304; e += 256){   // 144 nodes x 16 float4
        int m = e >> 4, k4 = e & 15;
        int hr = m/12, hc = m - (m/12)*12;
        int r = min(63,max(0,r0+hr)), c = min(63,max(0,c0+hc));
        float4 vv = *(const float4*)&HIN[(long)(nb + r*64 + c)*64 + k4*4];
        unsigned int p0 = (unsigned int)bfr(vv.x) | ((unsigned int)bfr(vv.y)<<16);
        unsigned int p1 = (unsigned int)bfr(vv.z) | ((unsigned int)bfr(vv.w)<<16);
        *(uint2*)&hA[m*72 + k4*4] = make_uint2(p0, p1);
    }
    __syncthreads();

    run_stage<PAIR,true >(t,w,lane,tr,tc,b, hA,xlb,alh,as2,ad2,x0h,kA,s1p,s2p,
                          cE,As,Ad,WgTh,WgTl,b_gat,g_f,bt_f, Hc,ACC,OUT);
    __syncthreads();
    run_stage<PAIR,false>(t,w,lane,tr,tc,b, hA,xlb,alh,as2,ad2,x0h,kA,s1p,s2p,
                          cE,As,Ad,WgTh,WgTl,b_gat,g_f,bt_f, Hc,ACC,OUT);
}

// ---- head: LN + MLP + fire override ----
__global__ __launch_bounds__(256) void head_kernel(
    const float* __restrict__ H, const float* __restrict__ x,
    const float* __restrict__ g_h, const float* __restrict__ bt_h,
    const float* __restrict__ Wh1, const float* __restrict__ bh1,
    const float* __restrict__ Wh2, const float* __restrict__ bh2,
    float* __restrict__ out)
{
    __shared__ __align__(16) float sm[4624];
    float* hT = sm;          // [64][68]
    float* pl = sm + 4352;   // [4][68]

    int t = threadIdx.x;
    int w = __builtin_amdgcn_readfirstlane(t >> 6);
    int lane = t & 63;
    int n0 = blockIdx.x * 64;
    int b = n0 >> 12;
    int cell0 = n0 & 4095;

    for (int e = t; e < 4096; e += 256){
        int n = e >> 6, j = e & 63;
        hT[j*68 + n] = H[(n0+n)*64 + j];
    }
    __syncthreads();

    float s1 = 0.f, s2 = 0.f;
    for (int j = 0; j < 64; j++){
        float v = hT[j*68 + lane];
        s1 += v; s2 += v*v;
    }
    float mean = s1*(1.f/64.f);
    float var  = s2*(1.f/64.f) - mean*mean;
    float rstd = rsqrtf(fmaxf(var, 0.f) + 1e-5f);

    float acc[16];
    #pragma unroll
    for (int kk = 0; kk < 16; kk++) acc[kk] = bh1[w*16 + kk];
    for (int j = 0; j < 64; j++){
        float v = (hT[j*68 + lane] - mean)*rstd*g_h[j] + bt_h[j];
        #pragma unroll
        for (int kk = 0; kk < 16; kk++)
            acc[kk] += v * Wh1[j*64 + w*16 + kk];
    }
    float plg = 0.f;
    #pragma unroll
    for (int kk = 0; kk < 16; kk++){
        float a = acc[kk];
        plg += (a * sigmoidf_(a)) * Wh2[w*16 + kk];
    }
    pl[w*68 + lane] = plg;
    __syncthreads();
    if (t < 64){
        float lgt = pl[0*68+t] + pl[1*68+t] + pl[2*68+t] + pl[3*68+t] + bh2[0];
        float fire = x[b*(12*NN) + cell0 + t];
        out[n0 + t] = (fire > 0.5f) ? fmaxf(lgt, 6.f) : lgt;
    }
}

extern "C" void kernel_launch(void* const* d_in, const int* in_sizes, int n_in,
                              void* d_out, int out_size, void* d_ws, size_t ws_size,
                              hipStream_t stream)
{
    const float* x       = (const float*)d_in[0];
    const float* W_enc1  = (const float*)d_in[3];
    const float* b_enc1  = (const float*)d_in[4];
    const float* W_enc2  = (const float*)d_in[5];
    const float* b_enc2  = (const float*)d_in[6];
    const float* W_gat   = (const float*)d_in[7];
    const float* att_src = (const float*)d_in[8];
    const float* att_dst = (const float*)d_in[9];
    const float* W_edge  = (const float*)d_in[10];
    const float* att_edge= (const float*)d_in[11];
    const float* b_gat   = (const float*)d_in[12];
    const float* g_f     = (const float*)d_in[13];
    const float* bt_f    = (const float*)d_in[14];
    const float* g_h     = (const float*)d_in[15];
    const float* bt_h    = (const float*)d_in[16];
    const float* W_h1    = (const float*)d_in[17];
    const float* b_h1    = (const float*)d_in[18];
    const float* W_h2    = (const float*)d_in[19];
    const float* b_h2    = (const float*)d_in[20];

    float* ws  = (float*)d_ws;
    float* H0  = ws;                 // [BN][64]
    float* H1  = ws + 2097152;       // [BN][64]
    float* T1  = ws + 4194304;       // [BN][64]
    float* ACC = ws + 6291456;       // [BN][64]
    float* CAS = ws + 8388608;       // [64][4]
    float* CAD = ws + 8388864;       // [64][4]
    float* CCE = ws + 8389120;       // [4][3]
    unsigned short* WgTh = (unsigned short*)(ws + 8389248);  // [256][64] bf16
    unsigned short* WgTl = (unsigned short*)(ws + 8397440);  // [256][64] bf16
    float* out = (float*)d_out;

    prep_kernel<<<1, 256, 0, stream>>>(W_gat, att_src, att_dst, W_edge, att_edge,
                                       CAS, CAD, CCE, WgTh, WgTl);
    enc_kernel<<<512, 256, 0, stream>>>(x, W_enc1, b_enc1, W_enc2, b_enc2, H0);

    float* Hcur = H0; float* Hnxt = H1;
    for (int step = 0; step < 4; step++){
        f2_kernel<0><<<512, 256, 0, stream>>>(Hcur, Hcur, x, CCE, CAS, CAD, WgTh, WgTl,
                                              b_gat, g_f, bt_f, ACC, T1);
        f2_kernel<1><<<512, 256, 0, stream>>>(T1, Hcur, x, CCE, CAS, CAD, WgTh, WgTl,
                                              b_gat, g_f, bt_f, ACC, Hnxt);
        float* tm = Hcur; Hcur = Hnxt; Hnxt = tm;
    }

    head_kernel<<<512, 256, 0, stream>>>(Hcur, x, g_h, bt_h, W_h1, b_h1, W_h2, b_h2, out);
}